// Round 10
// baseline (562.508 us; speedup 1.0000x reference)
//
#include <hip/hip_runtime.h>
#include <hip/hip_bf16.h>

#define N_NODES 8192
#define NF      256
#define L2E     1.44269504088896341f

typedef __attribute__((ext_vector_type(8))) short short8;
typedef __attribute__((ext_vector_type(4))) short short4v;
typedef __attribute__((ext_vector_type(4))) float floatx4;
typedef __attribute__((ext_vector_type(16))) float floatx16;

static __device__ __forceinline__ float bf2f(short s) {
    return __uint_as_float(((unsigned)(unsigned short)s) << 16);
}
static __device__ __forceinline__ short f2bf_rn(float f) {
    unsigned u = __float_as_uint(f) + 0x8000u;
    return (short)(u >> 16);
}
struct bfpair { short hi, lo; };
static __device__ __forceinline__ bfpair split_bf(float x) {
    bfpair p;
    p.hi = f2bf_rn(x);
    p.lo = f2bf_rn(x - bf2f(p.hi));
    return p;
}
// async global->LDS, 16B/lane, LDS dest = uniform base + lane*16
static __device__ __forceinline__ void async16(const void* g, void* l) {
    __builtin_amdgcn_global_load_lds(
        (const __attribute__((address_space(1))) unsigned*)g,
        (__attribute__((address_space(3))) unsigned*)l, 16, 0, 0);
}

// ---------------------------------------------------------------------------
// KX: split W into bf16 hi/lo, once.
// ---------------------------------------------------------------------------
__global__ __launch_bounds__(256) void kx_split(const float* __restrict__ W,
                                                short* __restrict__ Whi,
                                                short* __restrict__ Wlo) {
    #pragma unroll
    for (int e = 0; e < 4; ++e) {
        const int i = blockIdx.x * 1024 + e * 256 + threadIdx.x;
        bfpair p = split_bf(W[i]);
        Whi[i] = p.hi;
        Wlo[i] = p.lo;
    }
}

// ---------------------------------------------------------------------------
// K1: WhT[n][i] = X@W^T via hi/lo bf16 MFMA + s partials. (unchanged)
// ---------------------------------------------------------------------------
__global__ __launch_bounds__(512) void k1_gemm(const float* __restrict__ X,
                                               const short* __restrict__ Whi,
                                               const short* __restrict__ Wlo,
                                               const float* __restrict__ r,
                                               short* __restrict__ WhT,
                                               float* __restrict__ sp_src,
                                               float* __restrict__ sp_dst) {
    __shared__ float Xs[32 * 256];

    const int tid = threadIdx.x;
    const int w = tid >> 6, lane = tid & 63;
    const int q = lane >> 4, m = lane & 15;
    const int rh = w >> 2, cq = w & 3;
    const int i_base = blockIdx.x * 32;

    #pragma unroll
    for (int v = 0; v < 4; ++v) {
        const int rowv = w * 4 + v;
        const int c = lane ^ (rowv & 7);
        async16(X + (size_t)(i_base + rowv) * NF + c * 4, &Xs[rowv * 256]);
    }
    __syncthreads();

    floatx4 acc[4] = {};
    const int xrow = rh * 16 + m;
    const int r7 = xrow & 7;
    #pragma unroll
    for (int ks = 0; ks < 8; ++ks) {
        const int c0 = ks * 8 + q * 2;
        float4 f0 = *(const float4*)(&Xs[xrow * 256 + ((c0 ^ r7) * 4)]);
        float4 f1 = *(const float4*)(&Xs[xrow * 256 + (((c0 + 1) ^ r7) * 4)]);
        const float xsv[8] = {f0.x, f0.y, f0.z, f0.w, f1.x, f1.y, f1.z, f1.w};
        short8 xh, xl;
        #pragma unroll
        for (int c = 0; c < 8; ++c) {
            bfpair p = split_bf(xsv[c]);
            xh[c] = p.hi; xl[c] = p.lo;
        }
        #pragma unroll
        for (int nt = 0; nt < 4; ++nt) {
            const int n = cq * 64 + nt * 16 + m;
            short8 wh = *(const short8*)(Whi + n * NF + ks * 32 + q * 8);
            short8 wl = *(const short8*)(Wlo + n * NF + ks * 32 + q * 8);
            acc[nt] = __builtin_amdgcn_mfma_f32_16x16x32_bf16(xh, wh, acc[nt], 0, 0, 0);
            acc[nt] = __builtin_amdgcn_mfma_f32_16x16x32_bf16(xl, wh, acc[nt], 0, 0, 0);
            acc[nt] = __builtin_amdgcn_mfma_f32_16x16x32_bf16(xh, wl, acc[nt], 0, 0, 0);
        }
    }

    const int i0 = i_base + rh * 16 + q * 4;
    float vs[4] = {0.f, 0.f, 0.f, 0.f}, vd[4] = {0.f, 0.f, 0.f, 0.f};
    #pragma unroll
    for (int nt = 0; nt < 4; ++nt) {
        const int n = cq * 64 + nt * 16 + m;
        short4v v;
        #pragma unroll
        for (int r2 = 0; r2 < 4; ++r2) v[r2] = f2bf_rn(acc[nt][r2]);
        *(short4v*)(WhT + (size_t)n * N_NODES + i0) = v;
        const float rs = r[n], rd = r[NF + n];
        #pragma unroll
        for (int r2 = 0; r2 < 4; ++r2) {
            vs[r2] = fmaf(acc[nt][r2], rs, vs[r2]);
            vd[r2] = fmaf(acc[nt][r2], rd, vd[r2]);
        }
    }
    #pragma unroll
    for (int mask = 1; mask <= 8; mask <<= 1) {
        #pragma unroll
        for (int r2 = 0; r2 < 4; ++r2) {
            vs[r2] += __shfl_xor(vs[r2], mask);
            vd[r2] += __shfl_xor(vd[r2], mask);
        }
    }
    if (m == 0) {
        #pragma unroll
        for (int r2 = 0; r2 < 4; ++r2) {
            sp_src[cq * N_NODES + i0 + r2] = vs[r2];
            sp_dst[cq * N_NODES + i0 + r2] = vd[r2];
        }
    }
}

// ---------------------------------------------------------------------------
// K2: sum partials -> s_src/s_dst; per-block max(s_dst) -> pmax[32]
// ---------------------------------------------------------------------------
__global__ __launch_bounds__(256) void k2_sv(const float* __restrict__ sp_src,
                                             const float* __restrict__ sp_dst,
                                             float* __restrict__ s_src,
                                             float* __restrict__ s_dst,
                                             float* __restrict__ pmax) {
    __shared__ float red[256];
    const int tid = threadIdx.x;
    const int i = blockIdx.x * 256 + tid;
    float ss = 0.f, sd = 0.f;
    #pragma unroll
    for (int nb = 0; nb < 4; ++nb) {
        ss += sp_src[nb * N_NODES + i];
        sd += sp_dst[nb * N_NODES + i];
    }
    s_src[i] = ss;
    s_dst[i] = sd;
    red[tid] = sd;
    __syncthreads();
    for (int off = 128; off > 0; off >>= 1) {
        if (tid < off) red[tid] = fmaxf(red[tid], red[tid + off]);
        __syncthreads();
    }
    if (tid == 0) pmax[blockIdx.x] = red[0];
}

// ---------------------------------------------------------------------------
// K3: bit-pack A. Apk[row][col'] byte, col' = jh*512 + g*64 + s (g=(2jq+lh)),
// byte bit b = A[row][jh*4096 + s*64 + g*8 + b] != 0.
// One wave per (row, jh): 64 coalesced dword loads of 64 j + __ballot.
// Pure HBM stream: 256 MB read, 8 MB write.
// ---------------------------------------------------------------------------
__global__ __launch_bounds__(256) void k3_pack(const int* __restrict__ Adj,
                                               unsigned char* __restrict__ Apk) {
    const int gid = blockIdx.x * 4 + (threadIdx.x >> 6);
    const int lane = threadIdx.x & 63;
    const int row = gid >> 1, jh = gid & 1;
    const int* base = Adj + (size_t)row * N_NODES + jh * 4096;

    unsigned long long accw = 0;
    #pragma unroll 4
    for (int it = 0; it < 64; ++it) {
        int v = base[it * 64 + lane];
        unsigned long long m = __ballot(v != 0);
        if (lane < 8) {
            unsigned long long byte = (m >> (lane * 8)) & 0xFFull;
            accw |= byte << ((it & 7) * 8);
            if ((it & 7) == 7) {
                *(unsigned long long*)(Apk + (size_t)row * 1024 + jh * 512 +
                                       lane * 64 + (it & ~7)) = accw;
                accw = 0;
            }
        }
    }
}

// ---------------------------------------------------------------------------
// K4: fused masked-softmax num/den partials (32x32x16 MFMA), HBM-free loop.
// grid 1024 = 256 ib x 2 jh x 2 nhf; 256 thr (4 waves = 4 jq).
// Block: 32 rows x 4096 j x 128 n. Macro = 64 j; B dbuf 2x16KB (33KB LDS
// -> 4 blocks/CU). A from packed bits: one 8B L1 load per 8 macros/lane.
// A-frag(32x32): row=lane&31, k=(lane>>5)*8+idx. C/D: col=lane&31,
// row=(reg&3)+8*(reg>>2)+4*(lane>>5).
// ---------------------------------------------------------------------------
static __device__ __forceinline__ void pgroup8(unsigned ab, const floatx4 t0,
                                               const floatx4 t1, const float s_i,
                                               const float d_i, float* p) {
    #pragma unroll
    for (int c = 0; c < 4; ++c) {
        float sum = s_i + t0[c];
        float lr  = fmaxf(sum, 0.2f * sum);
        float pp  = __builtin_amdgcn_exp2f(fmaf(lr, L2E, d_i));
        p[c] = (ab & (1u << c)) ? pp : 0.0f;
    }
    #pragma unroll
    for (int c = 0; c < 4; ++c) {
        float sum = s_i + t1[c];
        float lr  = fmaxf(sum, 0.2f * sum);
        float pp  = __builtin_amdgcn_exp2f(fmaf(lr, L2E, d_i));
        p[4 + c] = (ab & (1u << (4 + c))) ? pp : 0.0f;
    }
}

__global__ __launch_bounds__(256, 4) void k4_attn(const unsigned char* __restrict__ Apk,
                                                  const short* __restrict__ WhT,
                                                  const float* __restrict__ s_dst,
                                                  const float* __restrict__ s_src,
                                                  const float* __restrict__ pmax,
                                                  float* __restrict__ nump,
                                                  float* __restrict__ denp) {
    __shared__ union {
        short B[2][128 * 64];    // [buf][n_loc][8 slots x 8 shorts], slot=c^(n&7)
        float red[4 * 16 * 64];  // epilogue: [w][reg][lane]
    } sm;
    __shared__ float denred[4 * 32];

    const int tid = threadIdx.x;
    const int w = tid >> 6, lane = tid & 63;        // w == jq
    const int jq = w;
    const int l31 = lane & 31, lh = lane >> 5;
    const int bid = (int)blockIdx.x;
    const int ib = bid >> 2, jh = (bid >> 1) & 1, nhf = bid & 1;
    const int i0 = ib * 32;
    const int row = i0 + l31;
    const int jbase = jh * 4096;

    float M = pmax[0];
    #pragma unroll
    for (int b = 1; b < 32; ++b) M = fmaxf(M, pmax[b]);
    const float s_i = s_src[row];
    const float e0 = s_i + M;
    const float d_i = -fmaxf(e0, 0.2f * e0) * L2E;   // c_i >= row max (leaky monotone)

    // ---- staging offsets: wave stages local n-rows w*32..w*32+31 (4 async16)
    int voff[4];
    #pragma unroll
    for (int v = 0; v < 4; ++v) {
        const int rn = w * 32 + v * 8 + (lane >> 3);
        const int c = (lane & 7) ^ (rn & 7);
        voff[v] = rn * N_NODES + c * 8;              // short offset
    }
    const short* gBbase = WhT + (size_t)(nhf * 128) * N_NODES + jbase;

    // ---- frag-read offsets: chunk g = jq*2+lh, slot = g^(n&7) ----
    const int g = jq * 2 + lh;
    int boff[4];
    #pragma unroll
    for (int nt = 0; nt < 4; ++nt) {
        const int n = nt * 32 + l31;
        boff[nt] = n * 64 + ((g ^ (n & 7)) * 8);
    }

    // ---- packed-A pointer: lane needs cols g*64 + s, s=0..63 ----
    const unsigned char* aRow = Apk + (size_t)row * 1024 + jh * 512 + g * 64;
    const float* tPtr = s_dst + jbase + g * 8;

    floatx16 acc[4] = {};
    float den = 0.f;

    // ---- prologue: stage macro 0 -> buf0; load bit-group 0 ----
    #pragma unroll
    for (int v = 0; v < 4; ++v)
        async16(gBbase + voff[v], &sm.B[0][(w * 32 + v * 8) * 64]);
    unsigned long long abits = *(const unsigned long long*)(aRow);
    __syncthreads();

    for (int s8 = 0; s8 < 8; ++s8) {
        // prefetch next 8-macro bit group
        unsigned long long nabits = (s8 < 7)
            ? *(const unsigned long long*)(aRow + (s8 + 1) * 8) : 0ull;
        #pragma unroll
        for (int si = 0; si < 8; ++si) {
            const int s = s8 * 8 + si;
            const short* Bc = sm.B[s & 1];
            short* Bn = sm.B[(s & 1) ^ 1];

            // stage macro s+1 (async; lands during this macro's compute)
            if (s < 63) {
                const int jo = (s + 1) * 64;
                #pragma unroll
                for (int v = 0; v < 4; ++v)
                    async16(gBbase + jo + voff[v], Bn + (w * 32 + v * 8) * 64);
            }
            const unsigned ab = (unsigned)((abits >> (si * 8)) & 0xFFull);
            const float* tp = tPtr + s * 64;
            floatx4 t0 = *(const floatx4*)(tp);
            floatx4 t1 = *(const floatx4*)(tp + 4);

            float p[8];
            pgroup8(ab, t0, t1, s_i, d_i, p);

            short8 af;
            float ds = 0.f;
            #pragma unroll
            for (int c = 0; c < 8; ++c) { af[c] = f2bf_rn(p[c]); ds += p[c]; }
            den += ds;

            #pragma unroll
            for (int nt = 0; nt < 4; ++nt) {
                short8 b = *(const short8*)(Bc + boff[nt]);
                acc[nt] = __builtin_amdgcn_mfma_f32_32x32x16_bf16(af, b, acc[nt], 0, 0, 0);
            }
            __syncthreads();   // Bc reads done; staging into Bn landed
        }
        abits = nabits;
    }

    // ---- denominator partial: jq x lh slices tile j; reduce lh via shfl ----
    den += __shfl_xor(den, 32);
    if (lane < 32) denred[w * 32 + lane] = den;

    // ---- numerator: reduce 4 jq partials per nt via LDS -> nump[jh] ----
    float* numq = nump + (size_t)jh * N_NODES * NF;
    #pragma unroll
    for (int nt = 0; nt < 4; ++nt) {
        #pragma unroll
        for (int rg = 0; rg < 16; ++rg)
            sm.red[(w * 16 + rg) * 64 + lane] = acc[nt][rg];
        __syncthreads();
        if (nt == 0 && nhf == 0 && tid < 32) {
            float d = denred[tid] + denred[32 + tid] + denred[64 + tid] + denred[96 + tid];
            denp[jh * N_NODES + i0 + tid] = d;
        }
        #pragma unroll
        for (int k = 0; k < 4; ++k) {
            const int rg = w * 4 + k;
            float v = sm.red[((0 * 16) + rg) * 64 + lane]
                    + sm.red[((1 * 16) + rg) * 64 + lane]
                    + sm.red[((2 * 16) + rg) * 64 + lane]
                    + sm.red[((3 * 16) + rg) * 64 + lane];
            const int rrow = (rg & 3) + 8 * (rg >> 2) + 4 * lh;
            const int nn = nhf * 128 + nt * 32 + l31;
            numq[(size_t)(i0 + rrow) * NF + nn] = v;
        }
        __syncthreads();
    }
}

// ---------------------------------------------------------------------------
// K5: out = GELU( (num0+num1) / (den0+den1) )
// ---------------------------------------------------------------------------
__global__ __launch_bounds__(256) void k5_out(const float* __restrict__ nump,
                                              const float* __restrict__ denp,
                                              float* __restrict__ out) {
    const int idx = blockIdx.x * 256 + threadIdx.x;
    const int i = idx >> 8;
    float num = nump[idx] + nump[N_NODES * NF + idx];
    float den = denp[i] + denp[N_NODES + i];
    float x = num / fmaxf(den, 1e-30f);
    out[idx] = 0.5f * x * (1.0f + erff(x * 0.70710678118f));
}

// ---------------------------------------------------------------------------
extern "C" void kernel_launch(void* const* d_in, const int* in_sizes, int n_in,
                              void* d_out, int out_size, void* d_ws, size_t ws_size,
                              hipStream_t stream) {
    const float* X = (const float*)d_in[0];   // fp32 8192x256
    const int*   A = (const int*)d_in[1];     // int32 8192x8192
    const float* W = (const float*)d_in[2];   // fp32 256x256
    const float* r = (const float*)d_in[3];   // fp32 512
    float* out = (float*)d_out;

    char* wsp = (char*)d_ws;
    short* WhT    = (short*)wsp;                    wsp += (size_t)NF * N_NODES * 2;
    short* Whi    = (short*)wsp;                    wsp += NF * NF * 2;
    short* Wlo    = (short*)wsp;                    wsp += NF * NF * 2;
    float* sp_src = (float*)wsp;                    wsp += 4 * N_NODES * 4;
    float* sp_dst = (float*)wsp;                    wsp += 4 * N_NODES * 4;
    float* s_src  = (float*)wsp;                    wsp += N_NODES * 4;
    float* s_dst  = (float*)wsp;                    wsp += N_NODES * 4;
    float* pmax   = (float*)wsp;                    wsp += 32 * 4;
    float* denp   = (float*)wsp;                    wsp += 2 * N_NODES * 4;
    float* nump   = (float*)wsp;                    wsp += (size_t)2 * N_NODES * NF * 4;
    unsigned char* Apk = (unsigned char*)wsp;       // 8 MB

    kx_split<<<64, 256, 0, stream>>>(W, Whi, Wlo);
    k1_gemm<<<256, 512, 0, stream>>>(X, Whi, Wlo, r, WhT, sp_src, sp_dst);
    k2_sv<<<32, 256, 0, stream>>>(sp_src, sp_dst, s_src, s_dst, pmax);
    k3_pack<<<4096, 256, 0, stream>>>(A, Apk);
    k4_attn<<<1024, 256, 0, stream>>>(Apk, WhT, s_dst, s_src, pmax, nump, denp);
    k5_out<<<N_NODES * NF / 256, 256, 0, stream>>>(nump, denp, out);
}